// Round 4
// baseline (138.232 us; speedup 1.0000x reference)
//
#include <hip/hip_runtime.h>
#include <hip/hip_bf16.h>
#include <math.h>

// KAN layer: out = GELU( einsum('bik,ikj->bj', basis, W) + bias ),
//   basis[b,i,k] = x[b,i]^k, B=4096, D=1024, K=5, U=1024.
//
// Round 7: prep lane rewritten, GEMM frozen (proven 48us loop from r6).
//  (1) basis-pack loads were a 16-way scatter (lane = row, rows 4KB apart).
//      Now: coalesced 16x256 fp32 tile -> LDS (pad 260) -> transposed read,
//      powers, packed 1KB-burst stores. Load side goes from 16 lines per
//      wave-instruction at 25% utilization to 1KB dense bursts.
//  (2) basis + w_pack + fold merged into ONE kernel (1088 blocks): w-part
//      block owns a full n16 column, so the k=0 fold reduces in-block
//      (shfl + LDS) and writes b2 = bias + fold directly -- no atomics,
//      no init dispatch. Dispatches 3 -> 2.

#define B_DIM 4096
#define D_DIM 1024
#define U_DIM 1024
#define KT2 4096            // GEMM K after dropping k=0 plane
#define NKB 128             // 32-wide k-blocks

typedef unsigned short ushort_t;
typedef __attribute__((ext_vector_type(8))) short bf16x8;   // MFMA A/B frag
typedef __attribute__((ext_vector_type(4))) float f32x4;    // MFMA C/D frag

__device__ __forceinline__ ushort_t f2bf(float f) {
  union { float f; unsigned int u; } v;
  v.f = f;
  unsigned int r = v.u + 0x7FFFu + ((v.u >> 16) & 1u);
  return (ushort_t)(r >> 16);
}

__device__ __forceinline__ void load_lds16(const ushort_t* g, ushort_t* l) {
  __builtin_amdgcn_global_load_lds(
      (const __attribute__((address_space(1))) ushort_t*)g,
      (__attribute__((address_space(3))) ushort_t*)l, 16, 0, 0);
}

__device__ __forceinline__ float gelu_exact(float v) {
  return 0.5f * v * (1.0f + erff(v * 0.70710678118654752f));
}

// packed addr (ushorts) of (row, k): ((row>>4)*NKB + (k>>5))*512
//                                     + (((k>>3)&3)*16 + (row&15))*8 + (k&7)

// ---------------- merged prep: basis-pack (blocks 0..1023) + w-pack/fold (1024..1087) ----------------
__global__ __launch_bounds__(256) void prep_kernel(
    const float* __restrict__ x, const float* __restrict__ W,
    const float* __restrict__ bias, ushort_t* __restrict__ Ap,
    ushort_t* __restrict__ Bp, float* __restrict__ b2) {
  __shared__ __align__(16) float lsh[16][260];   // basis: 16x256 tile (pad 260)

  const int bid  = blockIdx.x;
  const int t    = threadIdx.x;
  const int wave = t >> 6;
  const int lane = t & 63;
  const int m    = lane & 15;
  const int ko   = lane >> 4;

  if (bid < 1024) {
    // ---- basis part: m16 = bid>>2, k-group bx = bid&3 (kblk bx*32..+31) ----
    const int bx  = bid & 3;
    const int m16 = bid >> 2;
    const float* xbase = x + (size_t)m16 * 16 * D_DIM + bx * 256;
    // coalesced tile load: 4 x (wave reads 1KB dense)
#pragma unroll
    for (int p = 0; p < 4; ++p) {
      const int row = p * 4 + wave;
      const int c4  = lane;               // 0..63 -> cols c4*4..+3
      *(float4*)&lsh[row][c4 * 4] =
          *(const float4*)(xbase + (size_t)row * D_DIM + c4 * 4);
    }
    __syncthreads();
    // transposed read + powers + packed stores (1KB burst per wave per u)
#pragma unroll
    for (int u = 0; u < 8; ++u) {
      const int kl  = u * 4 + wave;       // local kblk 0..31
      const int col = kl * 8 + ko * 2;
      const float xa = lsh[m][col], xb = lsh[m][col + 1];
      const float xa2 = xa * xa, xb2 = xb * xb;
      ushort_t o[8];
      o[0] = f2bf(xa);  o[1] = f2bf(xa2);
      o[2] = f2bf(xa2 * xa); o[3] = f2bf(xa2 * xa2);
      o[4] = f2bf(xb);  o[5] = f2bf(xb2);
      o[6] = f2bf(xb2 * xb); o[7] = f2bf(xb2 * xb2);
      *(uint4*)(Ap + ((size_t)m16 * NKB + bx * 32 + kl) * 512 + lane * 8) =
          *(const uint4*)o;
    }
  } else {
    // ---- w part: block owns n16 = bid-1024 (16 output cols, all 128 kblks) ----
    const int n16 = bid - 1024;           // 0..63
    const int j   = n16 * 16 + m;
    float s0 = 0.0f;
#pragma unroll 2
    for (int it2 = 0; it2 < 32; ++it2) {
      const int kblk = it2 * 4 + wave;    // waves cover kblk 0..127
      const int i0   = kblk * 8 + ko * 2;
      ushort_t o[8];
#pragma unroll
      for (int t2 = 0; t2 < 2; ++t2) {
        const int i = i0 + t2;
        s0 += W[(size_t)(i * 5) * U_DIM + j];         // k=0 plane
#pragma unroll
        for (int e = 0; e < 4; ++e)
          o[t2 * 4 + e] = f2bf(W[(size_t)(i * 5 + e + 1) * U_DIM + j]);
      }
      *(uint4*)(Bp + ((size_t)n16 * NKB + kblk) * 512 + lane * 8) =
          *(const uint4*)o;
    }
    // fold reduce: ko groups within wave, then across the 4 waves via LDS
    s0 += __shfl_xor(s0, 16, 64);
    s0 += __shfl_xor(s0, 32, 64);
    float* red = &lsh[0][0];
    __syncthreads();
    if (ko == 0) red[wave * 16 + m] = s0;
    __syncthreads();
    if (wave == 0 && ko == 0)
      b2[j] = bias[j] + red[m] + red[16 + m] + red[32 + m] + red[48 + m];
  }
}

// ---------------- main GEMM: 64x128 tile, BK=32, 4-buf counted-vmcnt, x4 unroll ----------------
// (FROZEN from r6 except epilogue reads pre-summed b2.)
// buffer layout: unit u = r (r 0..3 = A m16 r, r 4..11 = B n16 r-4).
// 12 KB per buffer, x4 = 48 KB. Prefetch distance 3, wait vmcnt(6): stages
// it+1, it+2 (2 x 3 loads/thread) stay in flight across the barrier.
__global__ __launch_bounds__(256) void gemm_kernel(
    const ushort_t* __restrict__ Ap, const ushort_t* __restrict__ Bp,
    const float* __restrict__ b2, float* __restrict__ C) {
  __shared__ __align__(16) ushort_t lds[4][12 * 512];   // 4 x 12 KB

  const int tid  = threadIdx.x;
  const int wave = tid >> 6;
  const int lane = tid & 63;
  const int wm   = wave >> 1;             // 0..1 : 32-row half
  const int wn   = wave & 1;              // 0..1 : 64-col half

  // XCD swizzle (bijective, 512 = 8 xcd * 64): each XCD owns an 8m x 8n
  // chunk, exactly co-resident on its 32 CUs (2 blocks/CU). Ap slice = 4 MB.
  const int lin  = blockIdx.y * 8 + blockIdx.x;
  const int xcd  = lin & 7;
  const int slot = lin >> 3;              // 0..63
  const int mt   = xcd * 8 + (slot & 7);  // 0..63
  const int nt   = slot >> 3;             // 0..7
  const int m16b = mt * 4;
  const int n16b = nt * 8;

  // staging assignment: s=0..2, unit u = s*4 + wave (dense 1 KB bursts)
  const ushort_t* gcur[3];
  int ldst[3];
#pragma unroll
  for (int s = 0; s < 3; ++s) {
    const int u = s * 4 + wave;           // 0..11
    const ushort_t* base = (u < 4)
        ? Ap + ((size_t)(m16b + u) * NKB) * 512
        : Bp + ((size_t)(n16b + (u - 4)) * NKB) * 512;
    gcur[s] = base + lane * 8;
    ldst[s] = u * 512 + lane * 8;
  }

  f32x4 acc[2][4];
  const f32x4 zero = {0.0f, 0.0f, 0.0f, 0.0f};
#pragma unroll
  for (int mf = 0; mf < 2; ++mf)
#pragma unroll
    for (int nf = 0; nf < 4; ++nf) acc[mf][nf] = zero;

#define WAITBAR(N) \
  asm volatile("s_waitcnt vmcnt(" #N ")\n\ts_barrier" ::: "memory")

// stage k-block at literal ushort-offset REL*512 from the rolling pointer
#define STAGE_REL(bb, rel)                                              \
  do {                                                                  \
    _Pragma("unroll")                                                   \
    for (int s = 0; s < 3; ++s)                                         \
      load_lds16(gcur[s] + (rel) * 512, &lds[bb][ldst[s]]);             \
  } while (0)

#define COMPUTE(bb)                                                     \
  do {                                                                  \
    bf16x8 a[2], b[4];                                                  \
    _Pragma("unroll")                                                   \
    for (int mf = 0; mf < 2; ++mf)                                      \
      a[mf] = *(const bf16x8*)&lds[bb][(wm * 2 + mf) * 512 + lane * 8]; \
    _Pragma("unroll")                                                   \
    for (int nf = 0; nf < 4; ++nf)                                      \
      b[nf] = *(const bf16x8*)&lds[bb][(4 + wn * 4 + nf) * 512 + lane * 8]; \
    _Pragma("unroll")                                                   \
    for (int mf = 0; mf < 2; ++mf)                                      \
      _Pragma("unroll")                                                 \
      for (int nf = 0; nf < 4; ++nf)                                    \
        acc[mf][nf] = __builtin_amdgcn_mfma_f32_16x16x32_bf16(          \
            a[mf], b[nf], acc[mf][nf], 0, 0, 0);                        \
  } while (0)

  // prologue: stage k-blocks 0..2 into buffers 0..2 (9 loads in flight)
  STAGE_REL(0, 0);
  STAGE_REL(1, 1);
  STAGE_REL(2, 2);
#pragma unroll
  for (int s = 0; s < 3; ++s) gcur[s] += 4 * 512;   // rebase: rel 0 == k-block 4

  // main loop, chunks of 4: it = base..base+3 computes buffers 0..3,
  // stages k-blocks base+3..base+6 into buffers 3,0,1,2.
  for (int base = 0; base < 124; base += 4) {
    WAITBAR(6); STAGE_REL(3, -1); COMPUTE(0);   // stage base+3
    WAITBAR(6); STAGE_REL(0,  0); COMPUTE(1);   // stage base+4
    WAITBAR(6); STAGE_REL(1,  1); COMPUTE(2);   // stage base+5
    WAITBAR(6); STAGE_REL(2,  2); COMPUTE(3);   // stage base+6
#pragma unroll
    for (int s = 0; s < 3; ++s) gcur[s] += 4 * 512;
  }
  // tail: it = 124..127 (gcur rel 0 == k-block 128)
  WAITBAR(6); STAGE_REL(3, -1); COMPUTE(0);     // stage 127
  WAITBAR(6); COMPUTE(1);
  WAITBAR(3); COMPUTE(2);
  WAITBAR(0); COMPUTE(3);
#undef STAGE_REL
#undef COMPUTE
#undef WAITBAR

  // epilogue: C/D map: col = lane&15, row = (lane>>4)*4 + reg
  const int crow0 = m16b * 16 + wm * 32 + (lane >> 4) * 4;
  const int ccol0 = n16b * 16 + wn * 64 + (lane & 15);
#pragma unroll
  for (int nf = 0; nf < 4; ++nf) {
    const int col = ccol0 + nf * 16;
    const float bv = b2[col];
#pragma unroll
    for (int mf = 0; mf < 2; ++mf) {
#pragma unroll
      for (int r = 0; r < 4; ++r) {
        const int row = crow0 + mf * 16 + r;
        C[(size_t)row * U_DIM + col] = gelu_exact(acc[mf][nf][r] + bv);
      }
    }
  }
}

// ---------------- fallback (ws too small): fp32, no workspace ----------------
__global__ void fallback_kernel(const float* __restrict__ x, const float* __restrict__ W,
                                const float* __restrict__ bias, float* __restrict__ out) {
  int j  = blockIdx.x * 256 + threadIdx.x;
  int b0 = blockIdx.y * 16;
  float acc[16];
#pragma unroll
  for (int t = 0; t < 16; ++t) acc[t] = 0.0f;
  for (int i = 0; i < D_DIM; ++i) {
    const float* wr = W + (size_t)i * 5 * U_DIM + j;
    float w0 = wr[0 * U_DIM], w1 = wr[1 * U_DIM], w2 = wr[2 * U_DIM];
    float w3 = wr[3 * U_DIM], w4 = wr[4 * U_DIM];
#pragma unroll
    for (int t = 0; t < 16; ++t) {
      float xv = x[(size_t)(b0 + t) * D_DIM + i];
      float x2 = xv * xv;
      acc[t] += w0 + xv * w1 + x2 * w2 + x2 * xv * w3 + x2 * x2 * w4;
    }
  }
  float bv = bias[j];
#pragma unroll
  for (int t = 0; t < 16; ++t)
    out[(size_t)(b0 + t) * U_DIM + j] = gelu_exact(acc[t] + bv);
}

extern "C" void kernel_launch(void* const* d_in, const int* in_sizes, int n_in,
                              void* d_out, int out_size, void* d_ws, size_t ws_size,
                              hipStream_t stream) {
  const float* x    = (const float*)d_in[0];   // (4096, 1024)
  const float* W    = (const float*)d_in[1];   // (1024, 5, 1024), row r = i*5+k
  const float* bias = (const float*)d_in[2];   // (1024,)
  float* out = (float*)d_out;                  // (4096, 1024) fp32

  const size_t szA = (size_t)B_DIM * KT2 * sizeof(ushort_t);   // 33.55 MB
  const size_t szB = (size_t)U_DIM * KT2 * sizeof(ushort_t);   //  8.39 MB
  const size_t szb = (size_t)U_DIM * sizeof(float);            //    4 KB

  if (ws_size >= szA + szB + szb) {
    ushort_t* Ap = (ushort_t*)d_ws;
    ushort_t* Bp = (ushort_t*)((char*)d_ws + szA);
    float*    b2 = (float*)((char*)d_ws + szA + szB);
    prep_kernel<<<dim3(1024 + 64), 256, 0, stream>>>(x, W, bias, Ap, Bp, b2);
    gemm_kernel<<<dim3(U_DIM / 128, B_DIM / 64), 256, 0, stream>>>(Ap, Bp, b2, out);
  } else {
    fallback_kernel<<<dim3(U_DIM / 256, B_DIM / 16), 256, 0, stream>>>(x, W, bias, out);
  }
}